// Round 1
// baseline (149.367 us; speedup 1.0000x reference)
//
#include <hip/hip_runtime.h>

// Problem constants: B=4, H=64, W=64, d=V=O=64, HW=4096
#define HW 4096
#define EPSF 1e-7f

// ws layout (float offsets):
//      0 : inv   [64*64]   1/variance
//   4096 : wiv   [64*64]   W/variance
//   8192 : Aq[64]  8256: Bq[64]  8320: Cq[64]
//   8384 : S1  [4*64*64]
//  24768 : S2p [4*64*64]
//  41152 : Qsp [4*64*64]
//  57536 : Zo  [4*64*64]
#define WS_INV 0
#define WS_WIV 4096
#define WS_A   8192
#define WS_B   8256
#define WS_C   8320
#define WS_S1  8384
#define WS_S2P 24768
#define WS_QSP 41152
#define WS_ZO  57536

__global__ __launch_bounds__(64) void k1_pre(const float* __restrict__ Wm,
                                             const float* __restrict__ var,
                                             float* __restrict__ ws) {
    int j = threadIdx.x;
    float a = 0.f, b = 0.f, c = 0.f;
    for (int i = 0; i < 64; i++) {
        float v = var[i * 64 + j];
        float w = Wm[i * 64 + j];
        float iv = 1.0f / v;
        ws[WS_INV + i * 64 + j] = iv;
        ws[WS_WIV + i * 64 + j] = w * iv;
        float iv2 = iv * iv;
        a += iv2;
        b += w * iv2;
        c += w * w * iv2;
    }
    ws[WS_A + j] = a;
    ws[WS_B + j] = b;
    ws[WS_C + j] = c;
}

// One block per (b, l): 64 rows n = l*64+i. Computes Q rows in-register and
// accumulates S1[b,l,j], S2 partial, Qsum partial. Q is NOT stored (recomputed in k4).
__global__ __launch_bounds__(256) void k2_q(const float* __restrict__ X,
                                            float* __restrict__ ws) {
    int b = blockIdx.x >> 6;
    int l = blockIdx.x & 63;
    int w = threadIdx.x >> 6;   // wave 0..3
    int j = threadIdx.x & 63;   // lane = column
    float Aj = ws[WS_A + j], Bj = ws[WS_B + j], Cj = ws[WS_C + j];
    float s1 = 0.f, s2 = 0.f, qsum = 0.f;
    for (int k = 0; k < 16; k++) {
        int i = w * 16 + k;          // row within the l-group
        int n = l * 64 + i;
        float x = X[((b * HW) + n) * 64 + j];
        float q = fmaf(fmaf(Aj, x, -2.0f * Bj), x, Cj);
        float m = q;
        for (int off = 1; off < 64; off <<= 1) m = fminf(m, __shfl_xor(m, off));
        float e = __expf(-0.5f * (q - m));
        float s = e;
        for (int off = 1; off < 64; off <<= 1) s += __shfl_xor(s, off);
        float Qv = e / s;
        s1 = fmaf(ws[WS_INV + i * 64 + j], Qv, s1);
        s2 = fmaf(ws[WS_WIV + i * 64 + j], Qv, s2);
        qsum += Qv;
    }
    __shared__ float red[3][4][64];
    red[0][w][j] = s1; red[1][w][j] = s2; red[2][w][j] = qsum;
    __syncthreads();
    if (threadIdx.x < 64) {
        float t1 = red[0][0][j] + red[0][1][j] + red[0][2][j] + red[0][3][j];
        float t2 = red[1][0][j] + red[1][1][j] + red[1][2][j] + red[1][3][j];
        float t3 = red[2][0][j] + red[2][1][j] + red[2][2][j] + red[2][3][j];
        int idx = (b * 64 + l) * 64 + j;
        ws[WS_S1 + idx] = t1;
        ws[WS_S2P + idx] = t2;
        ws[WS_QSP + idx] = t3;
    }
}

// One block per batch b (1024 threads = 16 waves).
// z[h,j] = sum_l X[b,h*64+l,j]*S1[l,j] - S2[j]; z=(z+eps)/(Qsum+eps);
// norm[j]=sum_h z^2; Z=z/norm; Adj=Z^T Z; out1=Z^T weight; Zo=relu(Adj@out1).
__global__ __launch_bounds__(1024) void k3_z(const float* __restrict__ X,
                                             const float* __restrict__ weight,
                                             float* __restrict__ ws) {
    int b = blockIdx.x;
    int tid = threadIdx.x;
    int g = tid >> 6;    // wave 0..15
    int j = tid & 63;    // lane
    __shared__ float s1l[64][65];
    __shared__ float zl[64][65];
    __shared__ float adj[64][65];
    __shared__ float o1[64][65];
    __shared__ float s2l[64], qsl[64], nrm[64];
    __shared__ float red[16][64];
    __shared__ float red2[16][64];

    // Load S1 tile; reduce S2/Qsum partials over l.
    {
        float ps2 = 0.f, pqs = 0.f;
        for (int k = 0; k < 4; k++) {
            int l = g * 4 + k;
            int idx = (b * 64 + l) * 64 + j;
            s1l[l][j] = ws[WS_S1 + idx];
            ps2 += ws[WS_S2P + idx];
            pqs += ws[WS_QSP + idx];
        }
        red[g][j] = ps2; red2[g][j] = pqs;
        __syncthreads();
        if (tid < 64) {
            float a = 0.f, c = 0.f;
            for (int t = 0; t < 16; t++) { a += red[t][j]; c += red2[t][j]; }
            s2l[j] = a; qsl[j] = c;
        }
        __syncthreads();
    }
    // z and norm
    {
        float nacc = 0.f;
        for (int k = 0; k < 4; k++) {
            int h = g * 4 + k;
            float acc = 0.f;
            const float* xp = X + ((size_t)(b * HW) + h * 64) * 64 + j;
            for (int l = 0; l < 64; l++) acc = fmaf(xp[l * 64], s1l[l][j], acc);
            float z = (acc - s2l[j] + EPSF) / (qsl[j] + EPSF);
            zl[h][j] = z;
            nacc = fmaf(z, z, nacc);
        }
        red[g][j] = nacc;
        __syncthreads();
        if (tid < 64) {
            float a = 0.f;
            for (int t = 0; t < 16; t++) a += red[t][j];
            nrm[j] = a;
        }
        __syncthreads();
        for (int k = 0; k < 4; k++) {
            int h = g * 4 + k;
            zl[h][j] = zl[h][j] / nrm[j];
        }
        __syncthreads();
    }
    // Adj[v][u] and out1[v][o]  (v = g + 16k; lane = u or o)
    {
        for (int k = 0; k < 4; k++) {
            int v = g + 16 * k;
            float a = 0.f;
            for (int h = 0; h < 64; h++) a = fmaf(zl[h][v], zl[h][j], a);
            adj[v][j] = a;
        }
        for (int k = 0; k < 4; k++) {
            int v = g + 16 * k;
            float a = 0.f;
            for (int h = 0; h < 64; h++) a = fmaf(zl[h][v], weight[h * 64 + j], a);
            o1[v][j] = a;
        }
        __syncthreads();
    }
    // out2 = Adj @ out1, relu, store Zo
    {
        for (int k = 0; k < 4; k++) {
            int v = g + 16 * k;
            float a = 0.f;
            for (int u = 0; u < 64; u++) a = fmaf(adj[v][u], o1[u][j], a);
            a = a > 0.f ? a : 0.f;
            ws[WS_ZO + (b * 64 + v) * 64 + j] = a;
        }
    }
}

// One block per (b, 64-row tile of n). Recompute Q rows into LDS, multiply by
// Zo, write output in (B,O,HW) layout coalesced.
__global__ __launch_bounds__(256) void k4_out(const float* __restrict__ X,
                                              const float* __restrict__ ws,
                                              float* __restrict__ out) {
    int b = blockIdx.x >> 6;
    int tb = blockIdx.x & 63;
    int nbase = tb * 64;
    int w = threadIdx.x >> 6;
    int lane = threadIdx.x & 63;
    __shared__ float qs[64][65];
    __shared__ float zo[64][65];
    for (int k = 0; k < 16; k++) {
        int idx = threadIdx.x + 256 * k;
        zo[idx >> 6][idx & 63] = ws[WS_ZO + b * 4096 + idx];
    }
    float Aj = ws[WS_A + lane], Bj = ws[WS_B + lane], Cj = ws[WS_C + lane];
    for (int k = 0; k < 16; k++) {
        int r = w * 16 + k;
        int n = nbase + r;
        float x = X[((b * HW) + n) * 64 + lane];
        float q = fmaf(fmaf(Aj, x, -2.0f * Bj), x, Cj);
        float m = q;
        for (int off = 1; off < 64; off <<= 1) m = fminf(m, __shfl_xor(m, off));
        float e = __expf(-0.5f * (q - m));
        float s = e;
        for (int off = 1; off < 64; off <<= 1) s += __shfl_xor(s, off);
        qs[r][lane] = e / s;
    }
    __syncthreads();
    // lane = local n row, wave covers 16 o's
    for (int k = 0; k < 16; k++) {
        int o = w * 16 + k;
        float acc = 0.f;
        for (int v = 0; v < 64; v++) acc = fmaf(qs[lane][v], zo[v][o], acc);
        out[(size_t)(b * 64 + o) * HW + nbase + lane] = acc;
    }
}

extern "C" void kernel_launch(void* const* d_in, const int* in_sizes, int n_in,
                              void* d_out, int out_size, void* d_ws, size_t ws_size,
                              hipStream_t stream) {
    const float* X      = (const float*)d_in[0];
    const float* Wm     = (const float*)d_in[1];
    const float* var    = (const float*)d_in[2];
    const float* weight = (const float*)d_in[3];
    float* ws  = (float*)d_ws;
    float* out = (float*)d_out;

    k1_pre<<<1, 64, 0, stream>>>(Wm, var, ws);
    k2_q<<<256, 256, 0, stream>>>(X, ws);
    k3_z<<<4, 1024, 0, stream>>>(X, weight, ws);
    k4_out<<<256, 256, 0, stream>>>(X, ws, out);
}

// Round 2
// 59.807 us; speedup vs baseline: 2.4975x; 2.4975x over previous
//
#include <hip/hip_runtime.h>

// Problem constants: B=4, H=64, W=64, d=V=O=64, HW=4096
#define HW 4096
#define EPSF 1e-7f

// ws layout (float offsets):
#define WS_INV 0          // [64*64] 1/variance
#define WS_WIV 4096       // [64*64] W/variance
#define WS_A   8192       // [64]
#define WS_B   8256       // [64]
#define WS_C   8320       // [64]
#define WS_S1  8384       // [4*64*64]
#define WS_S2P 24768      // [4*64*64]
#define WS_QSP 41152      // [4*64*64]
#define WS_ZO  57536      // [4*64*64]
#define WS_Z   73920      // [4*64*64]

__global__ __launch_bounds__(64) void k1_pre(const float* __restrict__ Wm,
                                             const float* __restrict__ var,
                                             float* __restrict__ ws) {
    int j = threadIdx.x;
    float a = 0.f, b = 0.f, c = 0.f;
    for (int i = 0; i < 64; i++) {
        float v = var[i * 64 + j];
        float w = Wm[i * 64 + j];
        float iv = 1.0f / v;
        ws[WS_INV + i * 64 + j] = iv;
        ws[WS_WIV + i * 64 + j] = w * iv;
        float iv2 = iv * iv;
        a += iv2;
        b += w * iv2;
        c += w * w * iv2;
    }
    ws[WS_A + j] = a;
    ws[WS_B + j] = b;
    ws[WS_C + j] = c;
}

// One block per (b, l): 64 rows n = l*64+i. Computes Q rows in-register and
// accumulates S1[b,l,j], S2 partial, Qsum partial. Q recomputed in k4.
__global__ __launch_bounds__(256) void k2_q(const float* __restrict__ X,
                                            float* __restrict__ ws) {
    int b = blockIdx.x >> 6;
    int l = blockIdx.x & 63;
    int w = threadIdx.x >> 6;   // wave 0..3
    int j = threadIdx.x & 63;   // lane = column
    float Aj = ws[WS_A + j], Bj = ws[WS_B + j], Cj = ws[WS_C + j];
    float s1 = 0.f, s2 = 0.f, qsum = 0.f;
    for (int k = 0; k < 16; k++) {
        int i = w * 16 + k;          // row within the l-group
        int n = l * 64 + i;
        float x = X[((b * HW) + n) * 64 + j];
        float q = fmaf(fmaf(Aj, x, -2.0f * Bj), x, Cj);
        float m = q;
        for (int off = 1; off < 64; off <<= 1) m = fminf(m, __shfl_xor(m, off));
        float e = __expf(-0.5f * (q - m));
        float s = e;
        for (int off = 1; off < 64; off <<= 1) s += __shfl_xor(s, off);
        float Qv = e / s;
        s1 = fmaf(ws[WS_INV + i * 64 + j], Qv, s1);
        s2 = fmaf(ws[WS_WIV + i * 64 + j], Qv, s2);
        qsum += Qv;
    }
    __shared__ float red[3][4][64];
    red[0][w][j] = s1; red[1][w][j] = s2; red[2][w][j] = qsum;
    __syncthreads();
    if (threadIdx.x < 64) {
        float t1 = red[0][0][j] + red[0][1][j] + red[0][2][j] + red[0][3][j];
        float t2 = red[1][0][j] + red[1][1][j] + red[1][2][j] + red[1][3][j];
        float t3 = red[2][0][j] + red[2][1][j] + red[2][2][j] + red[2][3][j];
        int idx = (b * 64 + l) * 64 + j;
        ws[WS_S1 + idx] = t1;
        ws[WS_S2P + idx] = t2;
        ws[WS_QSP + idx] = t3;
    }
}

// One block per (b, h): z[b,h,j] = sum_l X[b,h*64+l,j]*S1[b,l,j] - S2[b,j];
// z = (z + eps)/(Qsum[b,j] + eps). 256 blocks x 256 threads.
__global__ __launch_bounds__(256) void k3a_z(const float* __restrict__ X,
                                             float* __restrict__ ws) {
    int b = blockIdx.x >> 6;
    int h = blockIdx.x & 63;
    int w = threadIdx.x >> 6;
    int j = threadIdx.x & 63;
    float acc = 0.f, ps2 = 0.f, pqs = 0.f;
    for (int k = 0; k < 16; k++) {
        int l = w * 16 + k;
        float x = X[((size_t)(b * HW) + h * 64 + l) * 64 + j];
        int idx = (b * 64 + l) * 64 + j;
        acc = fmaf(x, ws[WS_S1 + idx], acc);
        ps2 += ws[WS_S2P + idx];
        pqs += ws[WS_QSP + idx];
    }
    __shared__ float ra[4][64], rb[4][64], rc[4][64];
    ra[w][j] = acc; rb[w][j] = ps2; rc[w][j] = pqs;
    __syncthreads();
    if (threadIdx.x < 64) {
        float a  = ra[0][j] + ra[1][j] + ra[2][j] + ra[3][j];
        float s2 = rb[0][j] + rb[1][j] + rb[2][j] + rb[3][j];
        float qs = rc[0][j] + rc[1][j] + rc[2][j] + rc[3][j];
        float z = (a - s2 + EPSF) / (qs + EPSF);
        ws[WS_Z + (b * 64 + h) * 64 + j] = z;
    }
}

// One block per batch (512 threads = 8 waves): norm, normalize, Adj = Z^T Z,
// out1 = Z^T weight, out2 = Adj@out1, relu -> Zo.
__global__ __launch_bounds__(512) void k3b_zo(const float* __restrict__ weight,
                                              float* __restrict__ ws) {
    int b = blockIdx.x;
    int tid = threadIdx.x;
    int g = tid >> 6;    // wave 0..7
    int j = tid & 63;
    __shared__ float zl[64][65];
    __shared__ float adj[64][65];
    __shared__ float o1[64][65];
    __shared__ float wl[64][65];
    __shared__ float red[8][64];
    __shared__ float nrm[64];
    for (int k = 0; k < 8; k++) {
        int idx = tid + 512 * k;
        zl[idx >> 6][idx & 63] = ws[WS_Z + b * 4096 + idx];
        wl[idx >> 6][idx & 63] = weight[idx];
    }
    __syncthreads();
    float nacc = 0.f;
    for (int k = 0; k < 8; k++) {
        int h = g * 8 + k;
        float z = zl[h][j];
        nacc = fmaf(z, z, nacc);
    }
    red[g][j] = nacc;
    __syncthreads();
    if (tid < 64) {
        float a = 0.f;
        for (int t = 0; t < 8; t++) a += red[t][j];
        nrm[j] = a;
    }
    __syncthreads();
    for (int k = 0; k < 8; k++) {
        int h = g * 8 + k;
        zl[h][j] = zl[h][j] / nrm[j];
    }
    __syncthreads();
    for (int k = 0; k < 8; k++) {
        int v = g * 8 + k;
        float aA = 0.f, aO = 0.f;
        for (int hh = 0; hh < 64; hh++) {
            float zv = zl[hh][v];           // wave-uniform broadcast
            aA = fmaf(zv, zl[hh][j], aA);
            aO = fmaf(zv, wl[hh][j], aO);
        }
        adj[v][j] = aA;
        o1[v][j] = aO;
    }
    __syncthreads();
    for (int k = 0; k < 8; k++) {
        int v = g * 8 + k;
        float a = 0.f;
        for (int u = 0; u < 64; u++) a = fmaf(adj[v][u], o1[u][j], a);
        a = a > 0.f ? a : 0.f;
        ws[WS_ZO + (b * 64 + v) * 64 + j] = a;
    }
}

// One block per (b, 64-row tile of n). Recompute Q rows into LDS, multiply by
// Zo, write output in (B,O,HW) layout coalesced.
__global__ __launch_bounds__(256) void k4_out(const float* __restrict__ X,
                                              const float* __restrict__ ws,
                                              float* __restrict__ out) {
    int b = blockIdx.x >> 6;
    int tb = blockIdx.x & 63;
    int nbase = tb * 64;
    int w = threadIdx.x >> 6;
    int lane = threadIdx.x & 63;
    __shared__ float qs[64][65];
    __shared__ float zo[64][65];
    for (int k = 0; k < 16; k++) {
        int idx = threadIdx.x + 256 * k;
        zo[idx >> 6][idx & 63] = ws[WS_ZO + b * 4096 + idx];
    }
    float Aj = ws[WS_A + lane], Bj = ws[WS_B + lane], Cj = ws[WS_C + lane];
    for (int k = 0; k < 16; k++) {
        int r = w * 16 + k;
        int n = nbase + r;
        float x = X[((b * HW) + n) * 64 + lane];
        float q = fmaf(fmaf(Aj, x, -2.0f * Bj), x, Cj);
        float m = q;
        for (int off = 1; off < 64; off <<= 1) m = fminf(m, __shfl_xor(m, off));
        float e = __expf(-0.5f * (q - m));
        float s = e;
        for (int off = 1; off < 64; off <<= 1) s += __shfl_xor(s, off);
        qs[r][lane] = e / s;
    }
    __syncthreads();
    for (int k = 0; k < 16; k++) {
        int o = w * 16 + k;
        float acc = 0.f;
        for (int v = 0; v < 64; v++) acc = fmaf(qs[lane][v], zo[v][o], acc);
        out[(size_t)(b * 64 + o) * HW + nbase + lane] = acc;
    }
}

extern "C" void kernel_launch(void* const* d_in, const int* in_sizes, int n_in,
                              void* d_out, int out_size, void* d_ws, size_t ws_size,
                              hipStream_t stream) {
    const float* X      = (const float*)d_in[0];
    const float* Wm     = (const float*)d_in[1];
    const float* var    = (const float*)d_in[2];
    const float* weight = (const float*)d_in[3];
    float* ws  = (float*)d_ws;
    float* out = (float*)d_out;

    k1_pre<<<1, 64, 0, stream>>>(Wm, var, ws);
    k2_q<<<256, 256, 0, stream>>>(X, ws);
    k3a_z<<<256, 256, 0, stream>>>(X, ws);
    k3b_zo<<<4, 512, 0, stream>>>(weight, ws);
    k4_out<<<256, 256, 0, stream>>>(X, ws, out);
}

// Round 3
// 27.377 us; speedup vs baseline: 5.4560x; 2.1846x over previous
//
#include <hip/hip_runtime.h>

// Problem constants: B=4, H=64, W=64, d=V=O=64, HW=4096
#define HW 4096
#define EPSF 1e-7f

// ws layout (float offsets):
#define WS_S1  0         // [4*64*64]  S1[b,l,j]
#define WS_S2P 16384     // [4*64*64]  S2 partial per l
#define WS_QSP 32768     // [4*64*64]  Qsum partial per l
#define WS_Z   49152     // [4*64*64]  z[b,a,j] (unnormalized)
#define WS_NRM 65536     // [4*64]     norm[b,j]
#define WS_IN2 65792     // [4*64]     1/norm^2
#define WS_G   66048     // [4*64*64]  G = z^T z
#define WS_P   82432     // [4*64*64]  P = z^T w
#define WS_ZO  98816     // [4*64*64]  Zo (post-relu)
#define WS_Q   115200    // [4*4096*64] Q

// ---------------------------------------------------------------------------
// kA: one block per (b,l). Computes A/B/C + inv/wiv in LDS (from W,var),
// then 64 Q rows (softmax per row), stores Q, accumulates S1/S2p/Qsp.
__global__ __launch_bounds__(256) void kA(const float* __restrict__ X,
                                          const float* __restrict__ Wm,
                                          const float* __restrict__ var,
                                          float* __restrict__ ws) {
    int b = blockIdx.x >> 6;
    int l = blockIdx.x & 63;
    int w = threadIdx.x >> 6;   // wave 0..3
    int j = threadIdx.x & 63;   // lane = column
    __shared__ float invl[64][64];   // (i*64+j)%32 = j%32: 2-way on access = free
    __shared__ float wivl[64][64];
    __shared__ float red[3][4][64];
    __shared__ float abc[3][64];

    float a = 0.f, bq = 0.f, c = 0.f;
#pragma unroll
    for (int k = 0; k < 16; k++) {
        int i = w * 16 + k;
        float v  = var[i * 64 + j];
        float wv = Wm[i * 64 + j];
        float iv = 1.0f / v;
        invl[i][j] = iv;
        wivl[i][j] = wv * iv;
        float iv2 = iv * iv;
        a  += iv2;
        bq += wv * iv2;
        c  += wv * wv * iv2;
    }
    red[0][w][j] = a; red[1][w][j] = bq; red[2][w][j] = c;
    __syncthreads();
    if (threadIdx.x < 64) {
        abc[0][j] = red[0][0][j] + red[0][1][j] + red[0][2][j] + red[0][3][j];
        abc[1][j] = red[1][0][j] + red[1][1][j] + red[1][2][j] + red[1][3][j];
        abc[2][j] = red[2][0][j] + red[2][1][j] + red[2][2][j] + red[2][3][j];
    }
    __syncthreads();
    float Aj = abc[0][j], Bj = abc[1][j], Cj = abc[2][j];

    float s1 = 0.f, s2 = 0.f, qsum = 0.f;
#pragma unroll
    for (int k = 0; k < 16; k++) {
        int i = w * 16 + k;
        int n = l * 64 + i;
        float x = X[((b * HW) + n) * 64 + j];
        float q = fmaf(fmaf(Aj, x, -2.0f * Bj), x, Cj);
        float m = q;
        for (int off = 1; off < 64; off <<= 1) m = fminf(m, __shfl_xor(m, off));
        float e = __expf(-0.5f * (q - m));
        float s = e;
        for (int off = 1; off < 64; off <<= 1) s += __shfl_xor(s, off);
        float Qv = e / s;
        ws[WS_Q + ((size_t)(b * HW) + n) * 64 + j] = Qv;
        s1 = fmaf(invl[i][j], Qv, s1);
        s2 = fmaf(wivl[i][j], Qv, s2);
        qsum += Qv;
    }
    __syncthreads();
    red[0][w][j] = s1; red[1][w][j] = s2; red[2][w][j] = qsum;
    __syncthreads();
    if (threadIdx.x < 64) {
        int idx = (b * 64 + l) * 64 + j;
        ws[WS_S1  + idx] = red[0][0][j] + red[0][1][j] + red[0][2][j] + red[0][3][j];
        ws[WS_S2P + idx] = red[1][0][j] + red[1][1][j] + red[1][2][j] + red[1][3][j];
        ws[WS_QSP + idx] = red[2][0][j] + red[2][1][j] + red[2][2][j] + red[2][3][j];
    }
}

// ---------------------------------------------------------------------------
// kB: one block per (b,a). z[b,a,j] = sum_l X[b,a*64+l,j]*S1[b,l,j] - S2[b,j];
// z = (z+eps)/(Qsum+eps). Stored unnormalized by norm (that folds later).
__global__ __launch_bounds__(256) void kB(const float* __restrict__ X,
                                          float* __restrict__ ws) {
    int b = blockIdx.x >> 6;
    int h = blockIdx.x & 63;
    int w = threadIdx.x >> 6;
    int j = threadIdx.x & 63;
    float acc = 0.f, ps2 = 0.f, pqs = 0.f;
#pragma unroll
    for (int k = 0; k < 16; k++) {
        int l = w * 16 + k;
        float x = X[((size_t)(b * HW) + h * 64 + l) * 64 + j];
        int idx = (b * 64 + l) * 64 + j;
        acc = fmaf(x, ws[WS_S1 + idx], acc);
        ps2 += ws[WS_S2P + idx];
        pqs += ws[WS_QSP + idx];
    }
    __shared__ float ra[4][64], rb[4][64], rc[4][64];
    ra[w][j] = acc; rb[w][j] = ps2; rc[w][j] = pqs;
    __syncthreads();
    if (threadIdx.x < 64) {
        float a  = ra[0][j] + ra[1][j] + ra[2][j] + ra[3][j];
        float s2 = rb[0][j] + rb[1][j] + rb[2][j] + rb[3][j];
        float qs = rc[0][j] + rc[1][j] + rc[2][j] + rc[3][j];
        ws[WS_Z + (b * 64 + h) * 64 + j] = (a - s2 + EPSF) / (qs + EPSF);
    }
}

// ---------------------------------------------------------------------------
// kD: 16 blocks per batch (vg=0..15). Loads z[b] + weight into LDS, computes
// norm redundantly, then G[v,:] = z^T z and P[v,:] = z^T w for v = vg*4 + wave.
__global__ __launch_bounds__(256) void kD(const float* __restrict__ weight,
                                          float* __restrict__ ws) {
    int b  = blockIdx.x >> 4;
    int vg = blockIdx.x & 15;
    int w4 = threadIdx.x >> 6;
    int j  = threadIdx.x & 63;
    __shared__ float zl[64][65];
    __shared__ float wl[64][65];
    __shared__ float red[4][64];
#pragma unroll
    for (int k = 0; k < 16; k++) {
        int idx = threadIdx.x + 256 * k;
        int r = idx >> 6, cc = idx & 63;
        zl[r][cc] = ws[WS_Z + b * 4096 + idx];
        wl[r][cc] = weight[idx];
    }
    __syncthreads();
    float na = 0.f;
#pragma unroll
    for (int k = 0; k < 16; k++) {
        int a = w4 * 16 + k;
        float zz = zl[a][j];
        na = fmaf(zz, zz, na);
    }
    red[w4][j] = na;
    __syncthreads();
    if (threadIdx.x < 64 && vg == 0) {
        float s = red[0][j] + red[1][j] + red[2][j] + red[3][j];
        ws[WS_NRM + b * 64 + j] = s;
        ws[WS_IN2 + b * 64 + j] = 1.0f / (s * s);
    }
    int v = vg * 4 + w4;
    float g = 0.f, p = 0.f;
#pragma unroll
    for (int d = 0; d < 64; d++) {
        float zdv = zl[d][v];     // wave-uniform broadcast
        g = fmaf(zdv, zl[d][j], g);
        p = fmaf(zdv, wl[d][j], p);
    }
    ws[WS_G + (b * 64 + v) * 64 + j] = g;
    ws[WS_P + (b * 64 + v) * 64 + j] = p;
}

// ---------------------------------------------------------------------------
// kE: out2[v,o] = (1/nrm[v]) * sum_u G[v,u]*in2[u]*P[u,o]; relu -> Zo.
// 16 blocks per batch, wave = one v.
__global__ __launch_bounds__(256) void kE(float* __restrict__ ws) {
    int b  = blockIdx.x >> 4;
    int vg = blockIdx.x & 15;
    int w4 = threadIdx.x >> 6;
    int o  = threadIdx.x & 63;
    __shared__ float Pl[64][65];
    __shared__ float gl[4][64];
#pragma unroll
    for (int k = 0; k < 16; k++) {
        int idx = threadIdx.x + 256 * k;
        Pl[idx >> 6][idx & 63] = ws[WS_P + b * 4096 + idx];
    }
    int v = vg * 4 + w4;
    gl[w4][o] = ws[WS_G + (b * 64 + v) * 64 + o] * ws[WS_IN2 + b * 64 + o];
    __syncthreads();
    float acc = 0.f;
#pragma unroll
    for (int u = 0; u < 64; u++) {
        acc = fmaf(gl[w4][u], Pl[u][o], acc);   // broadcast * coalesced
    }
    float nv = ws[WS_NRM + b * 64 + v];
    float r = acc / nv;
    r = r > 0.f ? r : 0.f;
    ws[WS_ZO + (b * 64 + v) * 64 + o] = r;
}

// ---------------------------------------------------------------------------
// kF: one block per (b, 64-row tile). Loads Q tile + Zo into LDS; rank-1
// update GEMM: thread owns (n=lane, o = wave*16..+15). Coalesced out writes.
__global__ __launch_bounds__(256) void kF(const float* __restrict__ ws,
                                          float* __restrict__ out) {
    int b = blockIdx.x >> 6;
    int tb = blockIdx.x & 63;
    int nbase = tb * 64;
    int w = threadIdx.x >> 6;
    int lane = threadIdx.x & 63;
    int w16 = w * 16;
    __shared__ float qs[64][65];
    __shared__ float zo[64][68];   // row stride 272B: 16B-aligned for float4
#pragma unroll
    for (int k = 0; k < 16; k++) {
        int idx = threadIdx.x + 256 * k;
        int r = idx >> 6, cc = idx & 63;
        qs[r][cc] = ws[WS_Q + ((size_t)(b * HW) + nbase + r) * 64 + cc];
        zo[r][cc] = ws[WS_ZO + b * 4096 + idx];
    }
    __syncthreads();
    float acc[16];
#pragma unroll
    for (int k = 0; k < 16; k++) acc[k] = 0.f;
#pragma unroll
    for (int v = 0; v < 64; v++) {
        float qv = qs[lane][v];
        float4 z0 = *(const float4*)&zo[v][w16];
        float4 z1 = *(const float4*)&zo[v][w16 + 4];
        float4 z2 = *(const float4*)&zo[v][w16 + 8];
        float4 z3 = *(const float4*)&zo[v][w16 + 12];
        acc[0]  = fmaf(qv, z0.x, acc[0]);
        acc[1]  = fmaf(qv, z0.y, acc[1]);
        acc[2]  = fmaf(qv, z0.z, acc[2]);
        acc[3]  = fmaf(qv, z0.w, acc[3]);
        acc[4]  = fmaf(qv, z1.x, acc[4]);
        acc[5]  = fmaf(qv, z1.y, acc[5]);
        acc[6]  = fmaf(qv, z1.z, acc[6]);
        acc[7]  = fmaf(qv, z1.w, acc[7]);
        acc[8]  = fmaf(qv, z2.x, acc[8]);
        acc[9]  = fmaf(qv, z2.y, acc[9]);
        acc[10] = fmaf(qv, z2.z, acc[10]);
        acc[11] = fmaf(qv, z2.w, acc[11]);
        acc[12] = fmaf(qv, z3.x, acc[12]);
        acc[13] = fmaf(qv, z3.y, acc[13]);
        acc[14] = fmaf(qv, z3.z, acc[14]);
        acc[15] = fmaf(qv, z3.w, acc[15]);
    }
#pragma unroll
    for (int k = 0; k < 16; k++) {
        int o = w16 + k;
        out[(size_t)(b * 64 + o) * HW + nbase + lane] = acc[k];
    }
}

extern "C" void kernel_launch(void* const* d_in, const int* in_sizes, int n_in,
                              void* d_out, int out_size, void* d_ws, size_t ws_size,
                              hipStream_t stream) {
    const float* X      = (const float*)d_in[0];
    const float* Wm     = (const float*)d_in[1];
    const float* var    = (const float*)d_in[2];
    const float* weight = (const float*)d_in[3];
    float* ws  = (float*)d_ws;
    float* out = (float*)d_out;

    kA<<<256, 256, 0, stream>>>(X, Wm, var, ws);
    kB<<<256, 256, 0, stream>>>(X, ws);
    kD<<<64, 256, 0, stream>>>(weight, ws);
    kE<<<64, 256, 0, stream>>>(ws);
    kF<<<256, 256, 0, stream>>>(ws, out);
}